// Round 7
// baseline (163.170 us; speedup 1.0000x reference)
//
#include <hip/hip_runtime.h>

typedef unsigned short u16;
typedef unsigned int u32;

typedef __bf16 bf16x8 __attribute__((ext_vector_type(8)));
typedef float f32x4 __attribute__((ext_vector_type(4)));

union V16 { uint4 u; bf16x8 v; u16 s[8]; __bf16 h[8]; };
union F4  { float4 v; float f[4]; };

__device__ __forceinline__ float bf2f(u16 a) {
  union { u32 u; float f; } c; c.u = ((u32)a) << 16; return c.f;
}

#define Z_OFF   131072
#define ZM_OFF  147456
#define ZLV_OFF 163840

// ws layout in uint4 units (decoder weights only now).
#define B1_OFF 0        // gen1_w: t<20, s<2   -> 2560
#define B2_OFF 2560     // gen2_w: t<20, s<10  -> 12800
#define WB4   15360     // W bf16 [512][64]    -> 4096
#define PACK_DEC_TOTAL 19456
#define PACK_DEC_BLOCKS 76       // x256 thr
// h1/h2 bf16 [256][320] staging (uint4 units)
#define H1_4 20480
#define H2_4 30720

__device__ __forceinline__ void pack_one(const float* __restrict__ src,
                                         int t, int s, int lane,
                                         int Nsrc, int Ksrc, int rowlen,
                                         uint4* __restrict__ dst) {
  const int n = t * 16 + (lane & 15);
  const int k0 = s * 32 + ((lane >> 4) << 3);
  V16 v;
#pragma unroll
  for (int j = 0; j < 8; ++j) {
    const int k = k0 + j;
    v.h[j] = (n < Nsrc && k < Ksrc) ? (__bf16)src[n * rowlen + k] : (__bf16)0.f;
  }
  *dst = v.u;
}

__device__ __forceinline__ void cvt8(const float* __restrict__ src, uint4* __restrict__ dst) {
  F4 a, b; a.v = *(const float4*)src; b.v = *(const float4*)(src + 4);
  V16 v;
#pragma unroll
  for (int j = 0; j < 4; ++j) { v.h[j] = (__bf16)a.f[j]; v.h[4 + j] = (__bf16)b.f[j]; }
  *dst = v.u;
}

// On-the-fly b-fragment from fp32 row-major [N][ld]; bit-identical to pack_one
// (verified R1). Elem j of lane = w[n][k0+j].
__device__ __forceinline__ uint4 mkfrag(const float* __restrict__ w, int n, int k0,
                                        int N, int K, int ld) {
  V16 v;
  if (n < N && k0 + 7 < K) {
    F4 a, b;
    a.v = *(const float4*)(w + n * ld + k0);
    b.v = *(const float4*)(w + n * ld + k0 + 4);
#pragma unroll
    for (int j = 0; j < 4; ++j) { v.h[j] = (__bf16)a.f[j]; v.h[4 + j] = (__bf16)b.f[j]; }
  } else if (n < N) {
#pragma unroll
    for (int j = 0; j < 8; ++j) {
      const int k = k0 + j;
      v.h[j] = (k < K) ? (__bf16)w[n * ld + k] : (__bf16)0.f;
    }
  } else {
    v.u = make_uint4(0u, 0u, 0u, 0u);
  }
  return v.u;
}

// ---------------------------------------------------------------------------
// Launch 1: blocks [0,320) = enc1 (rt 16 x nt 20), 256 thr (4 waves, split-K,
// self-packing x->LDS and e1w frags on the fly). Blocks [320,396) = decoder
// weight packing (independent of encoder -> safe in same launch).
// ---------------------------------------------------------------------------
__global__ __launch_bounds__(256) void enc1_kernel(
    const float* __restrict__ x,   const float* __restrict__ e1w,
    const float* __restrict__ e1b, u16* __restrict__ h1,
    const float* __restrict__ g1w, const float* __restrict__ g2w,
    const float* __restrict__ W,   uint4* __restrict__ ws4) {
  __shared__ uint4 xs[16 * 65];     // x tile bf16 [16][520] padded
  __shared__ float red[4 * 320];    // split-K partials, lane stride 5

  const int blk = blockIdx.x;
  const int tid = threadIdx.x;

  if (blk >= 320) {
    // ---- decoder weight pack (R0 pack verbatim, B1/B2/W sections) ----
    const int idx = (blk - 320) * 256 + tid;
    if (idx >= PACK_DEC_TOTAL) return;
    const int lane = idx & 63;
    if (idx < B2_OFF) {
      const int f = idx >> 6;
      pack_one(g1w, f >> 1, f & 1, lane, 300, 64, 64, ws4 + idx);
    } else if (idx < WB4) {
      const int f = (idx - B2_OFF) >> 6;
      pack_one(g2w, f / 10, f % 10, lane, 300, 300, 300, ws4 + idx);
    } else {
      const int i = idx - WB4;
      cvt8(W + i * 8, ws4 + WB4 + i);
    }
    return;
  }

  const int rt = blk / 20, nt = blk % 20;
  const int w = tid >> 6, lane = tid & 63, q = lane >> 4, c = lane & 15;
  const int r0 = rt * 16;

  // stage x rows -> LDS bf16 (coalesced; verified R1)
  for (int i = tid; i < 1024; i += 256) {
    const int row = i >> 6, kg = i & 63;
    cvt8(x + (r0 + row) * 512 + kg * 8, &xs[row * 65 + kg]);
  }
  __syncthreads();

  // split-K: wave w handles s = 4w..4w+3; b-frags built on the fly
  f32x4 acc = {0.f, 0.f, 0.f, 0.f};
  const int nbase = nt * 16 + c;
#pragma unroll
  for (int j = 0; j < 4; ++j) {
    const int s = 4 * w + j;
    V16 a, b;
    a.u = xs[c * 65 + s * 4 + q];
    b.u = mkfrag(e1w, nbase, s * 32 + q * 8, 300, 512, 512);
    acc = __builtin_amdgcn_mfma_f32_16x16x32_bf16(a.v, b.v, acc, 0, 0, 0);
  }
#pragma unroll
  for (int i = 0; i < 4; ++i) red[w * 320 + lane * 5 + i] = acc[i];
  __syncthreads();
  const int col = nt * 16 + c;
  float t = 0.f;
#pragma unroll
  for (int ww = 0; ww < 4; ++ww) t += red[ww * 320 + lane * 5 + w];
  const float bias = (col < 300) ? e1b[col] : 0.f;
  const int row = rt * 16 + 4 * q + w;
  V16 o; o.h[0] = (col < 300) ? (__bf16)fmaxf(t + bias, 0.f) : (__bf16)0.f;
  h1[row * 320 + col] = o.s[0];
}

// enc2: 320 WGs x 320 thr (5 waves, 2 K-steps each), self-packing e2w frags.
__global__ __launch_bounds__(320) void enc2_kernel(
    const uint4* __restrict__ h1, const float* __restrict__ e2w,
    const float* __restrict__ e2b, u16* __restrict__ h2) {
  __shared__ float red[5 * 320];
  const int wg = blockIdx.x;
  const int rt = wg / 20, nt = wg % 20;
  const int tid = threadIdx.x;
  const int w = tid >> 6, lane = tid & 63, q = lane >> 4, c = lane & 15;
  f32x4 acc = {0.f, 0.f, 0.f, 0.f};
  const int arow = rt * 16 + c;
  const int nbase = nt * 16 + c;
#pragma unroll
  for (int j = 0; j < 2; ++j) {
    const int s = 2 * w + j;
    V16 a, b;
    a.u = h1[arow * 40 + s * 4 + q];
    b.u = mkfrag(e2w, nbase, s * 32 + q * 8, 300, 300, 300);
    acc = __builtin_amdgcn_mfma_f32_16x16x32_bf16(a.v, b.v, acc, 0, 0, 0);
  }
#pragma unroll
  for (int i = 0; i < 4; ++i) red[w * 320 + lane * 5 + i] = acc[i];
  __syncthreads();
  if (w < 4) {
    const int col = nt * 16 + c;
    float t = 0.f;
#pragma unroll
    for (int ww = 0; ww < 5; ++ww) t += red[ww * 320 + lane * 5 + w];
    const float bias = (col < 300) ? e2b[col] : 0.f;
    const int row = rt * 16 + 4 * q + w;
    V16 o; o.h[0] = (col < 300) ? (__bf16)fmaxf(t + bias, 0.f) : (__bf16)0.f;
    h2[row * 320 + col] = o.s[0];
  }
}

// heads: 64 WGs x 320 thr (5 waves, 2 K-steps each), self-packing zm/zv frags.
__global__ __launch_bounds__(320) void ench_kernel(
    const uint4* __restrict__ h2, const float* __restrict__ eps,
    const float* __restrict__ zmw, const float* __restrict__ zmb,
    const float* __restrict__ zvw, const float* __restrict__ zvb,
    float* __restrict__ out) {
  __shared__ float redm[5 * 320];
  __shared__ float redv[5 * 320];
  const int wg = blockIdx.x;
  const int rt = wg >> 2, t = wg & 3;
  const int tid = threadIdx.x;
  const int w = tid >> 6, lane = tid & 63, q = lane >> 4, c = lane & 15;
  f32x4 am = {0.f, 0.f, 0.f, 0.f}, av = {0.f, 0.f, 0.f, 0.f};
  const int arow = rt * 16 + c;
  const int nbase = t * 16 + c;
#pragma unroll
  for (int j = 0; j < 2; ++j) {
    const int s = 2 * w + j;
    V16 a, bm, bv;
    a.u = h2[arow * 40 + s * 4 + q];
    bm.u = mkfrag(zmw, nbase, s * 32 + q * 8, 64, 300, 300);
    bv.u = mkfrag(zvw, nbase, s * 32 + q * 8, 64, 300, 300);
    am = __builtin_amdgcn_mfma_f32_16x16x32_bf16(a.v, bm.v, am, 0, 0, 0);
    av = __builtin_amdgcn_mfma_f32_16x16x32_bf16(a.v, bv.v, av, 0, 0, 0);
  }
#pragma unroll
  for (int i = 0; i < 4; ++i) {
    redm[w * 320 + lane * 5 + i] = am[i];
    redv[w * 320 + lane * 5 + i] = av[i];
  }
  __syncthreads();
  if (w < 4) {
    const int col = t * 16 + c;
    float tm = 0.f, tv = 0.f;
#pragma unroll
    for (int ww = 0; ww < 5; ++ww) {
      tm += redm[ww * 320 + lane * 5 + w];
      tv += redv[ww * 320 + lane * 5 + w];
    }
    const float zm = tm + zmb[col];
    const float zlv = tv + zvb[col];
    const int gi = (rt * 16 + 4 * q + w) * 64 + col;
    out[ZM_OFF + gi] = zm;
    out[ZLV_OFF + gi] = zlv;
    out[Z_OFF + gi] = zm + eps[gi] * expf(0.5f * zlv);
  }
}

// ---------------------------------------------------------------------------
// Fused decoder (R0 verbatim — the verified 79.6us kernel).
// 4096 WGs x 320 thr (5 waves). 32 rows/WG.
// ---------------------------------------------------------------------------
__global__ __launch_bounds__(320, 4) void dec_kernel(
    const float* __restrict__ z,     // [256][64] (fp32, in d_out)
    const uint4* __restrict__ Wb,    // bf16 [512][64]
    const uint4* __restrict__ b1p,
    const uint4* __restrict__ b2p,
    const float* __restrict__ g2b,
    const float* __restrict__ hw,    // [512][300] fp32
    const float* __restrict__ hb,
    float* __restrict__ xout) {
  __shared__ u16 g1s[32 * 328];     // 20,992 B (reused as xred after barrier)
  float* xredf = (float*)g1s;

  const int wg = blockIdx.x;
  const int r0 = wg << 5;
  const int bi = wg >> 4;
  const int d0 = r0 & 511;
  const int tid = threadIdx.x;
  const int u = tid >> 6;
  const int lane = tid & 63;
  const int q = lane >> 4;
  const int c = lane & 15;

  const float* zrow = z + bi * 64;

  // ---- stage 2 ----
  bf16x8 bz[4][2];
#pragma unroll
  for (int kf = 0; kf < 2; ++kf) {
    F4 z0, z1;
    z0.v = *(const float4*)(zrow + kf * 32 + q * 8);
    z1.v = *(const float4*)(zrow + kf * 32 + q * 8 + 4);
#pragma unroll
    for (int tt = 0; tt < 4; ++tt) {
      V16 r; r.u = b1p[((4 * u + tt) * 2 + kf) * 64 + lane];
      V16 m;
#pragma unroll
      for (int j = 0; j < 4; ++j) {
        m.h[j]     = (__bf16)(bf2f(r.s[j])     * z0.f[j]);
        m.h[4 + j] = (__bf16)(bf2f(r.s[4 + j]) * z1.f[j]);
      }
      bz[tt][kf] = m.v;
    }
  }
#pragma unroll
  for (int rt = 0; rt < 2; ++rt) {
    const int rowA = rt * 16 + c;
    V16 af0, af1;
    af0.u = Wb[(d0 + rowA) * 8 + q];
    af1.u = Wb[(d0 + rowA) * 8 + 4 + q];
    f32x4 acc[4];
#pragma unroll
    for (int tt = 0; tt < 4; ++tt) acc[tt] = {0.f, 0.f, 0.f, 0.f};
#pragma unroll
    for (int tt = 0; tt < 4; ++tt) {
      acc[tt] = __builtin_amdgcn_mfma_f32_16x16x32_bf16(af0.v, bz[tt][0], acc[tt], 0, 0, 0);
      acc[tt] = __builtin_amdgcn_mfma_f32_16x16x32_bf16(af1.v, bz[tt][1], acc[tt], 0, 0, 0);
    }
    const int rwb = rt * 16 + 4 * q;
#pragma unroll
    for (int tt = 0; tt < 4; ++tt) {
      const int colb = (4 * u + tt) * 16 + c;
#pragma unroll
      for (int i = 0; i < 4; ++i) {
        V16 t; t.h[0] = (__bf16)fmaxf(acc[tt][i], 0.f);
        g1s[(rwb + i) * 328 + colb] = t.s[0];
      }
    }
  }
  __syncthreads();

  // ---- stage 3 ----
  f32x4 a3[4][2];
#pragma unroll
  for (int tt = 0; tt < 4; ++tt)
#pragma unroll
    for (int rt = 0; rt < 2; ++rt) a3[tt][rt] = {0.f, 0.f, 0.f, 0.f};
  for (int s = 0; s < 10; ++s) {
    V16 b[4];
#pragma unroll
    for (int tt = 0; tt < 4; ++tt) b[tt].u = b2p[((4 * u + tt) * 10 + s) * 64 + lane];
#pragma unroll
    for (int rt = 0; rt < 2; ++rt) {
      V16 a; a.u = *(const uint4*)&g1s[(rt * 16 + c) * 328 + s * 32 + q * 8];
#pragma unroll
      for (int tt = 0; tt < 4; ++tt)
        a3[tt][rt] = __builtin_amdgcn_mfma_f32_16x16x32_bf16(a.v, b[tt].v, a3[tt][rt], 0, 0, 0);
    }
  }
  float xacc[2][4];
#pragma unroll
  for (int rt = 0; rt < 2; ++rt)
#pragma unroll
    for (int i = 0; i < 4; ++i) xacc[rt][i] = 0.f;
#pragma unroll
  for (int tt = 0; tt < 4; ++tt) {
    const int col = (4 * u + tt) * 16 + c;
    const bool inb = (col < 300);
    const float bias = inb ? g2b[col] : 0.f;
#pragma unroll
    for (int rt = 0; rt < 2; ++rt)
#pragma unroll
      for (int i = 0; i < 4; ++i) {
        const float g2v = fmaxf(a3[tt][rt][i] + bias, 0.f);
        const float h = inb ? hw[(d0 + rt * 16 + 4 * q + i) * 300 + col] : 0.f;
        xacc[rt][i] += g2v * h;
      }
  }
#pragma unroll
  for (int rt = 0; rt < 2; ++rt)
#pragma unroll
    for (int i = 0; i < 4; ++i) {
      float t = xacc[rt][i];
      t += __shfl_xor(t, 1);
      t += __shfl_xor(t, 2);
      t += __shfl_xor(t, 4);
      t += __shfl_xor(t, 8);
      xacc[rt][i] = t;
    }
  __syncthreads();
  if (c < 4) {
#pragma unroll
    for (int rt = 0; rt < 2; ++rt) {
      float t = xacc[rt][0];
      t = (c == 1) ? xacc[rt][1] : t;
      t = (c == 2) ? xacc[rt][2] : t;
      t = (c == 3) ? xacc[rt][3] : t;
      xredf[u * 32 + rt * 16 + 4 * q + c] = t;
    }
  }
  __syncthreads();
  if (tid < 32) {
    float t = hb[d0 + tid];
#pragma unroll
    for (int uu = 0; uu < 5; ++uu) t += xredf[uu * 32 + tid];
    xout[r0 + tid] = t;
  }
}

extern "C" void kernel_launch(void* const* d_in, const int* in_sizes, int n_in,
                              void* d_out, int out_size, void* d_ws, size_t ws_size,
                              hipStream_t stream) {
  const float* x   = (const float*)d_in[0];
  const float* eps = (const float*)d_in[1];
  const float* W   = (const float*)d_in[2];
  const float* e1w = (const float*)d_in[3];
  const float* e1b = (const float*)d_in[4];
  const float* e2w = (const float*)d_in[5];
  const float* e2b = (const float*)d_in[6];
  const float* zmw = (const float*)d_in[7];
  const float* zmb = (const float*)d_in[8];
  const float* zvw = (const float*)d_in[9];
  const float* zvb = (const float*)d_in[10];
  const float* g1w = (const float*)d_in[11];
  const float* g2w = (const float*)d_in[12];
  const float* g2b = (const float*)d_in[13];
  const float* hw  = (const float*)d_in[14];
  const float* hb  = (const float*)d_in[15];
  float* out = (float*)d_out;
  uint4* ws4 = (uint4*)d_ws;

  enc1_kernel<<<320 + PACK_DEC_BLOCKS, 256, 0, stream>>>(
      x, e1w, e1b, (u16*)(ws4 + H1_4), g1w, g2w, W, ws4);
  enc2_kernel<<<320, 320, 0, stream>>>(ws4 + H1_4, e2w, e2b, (u16*)(ws4 + H2_4));
  ench_kernel<<<64, 320, 0, stream>>>(ws4 + H2_4, eps, zmw, zmb, zvw, zvb, out);
  dec_kernel<<<4096, 320, 0, stream>>>(out + Z_OFF, ws4 + WB4,
                                       ws4 + B1_OFF, ws4 + B2_OFF,
                                       g2b, hw, hb, out);
}